// Round 8
// baseline (406.659 us; speedup 1.0000x reference)
//
#include <hip/hip_runtime.h>
#include <hip/hip_bf16.h>
#include <cstdint>
#include <cstddef>

#define B 64
#define T 1024
#define DQ 1024
#define DV 512
#define A_DIM 512
#define F_DIM 32
#define KW 31
#define M_TOT (B*T)
#define KEXT2 576     // DV + 64 (conv 32 + zero-pad 32)

typedef __attribute__((ext_vector_type(8))) short short8;
typedef __attribute__((ext_vector_type(4))) float f32x4;
typedef __attribute__((ext_vector_type(4))) unsigned u32x4;

static __device__ __forceinline__ unsigned short f2bf(float f) {
    unsigned int u = __builtin_bit_cast(unsigned int, f);
    u += 0x7fffu + ((u >> 16) & 1u);   // RNE
    return (unsigned short)(u >> 16);
}
static __device__ __forceinline__ float tanh_fast(float x) {
    float e = __expf(2.0f * x);
    return 1.0f - 2.0f * __builtin_amdgcn_rcpf(e + 1.0f);
}
// hardware packed fp32->bf16: one v_cvt_pk_bf16_f32 per element-pair
static __device__ __forceinline__ short8 cvt8(f32x4 a, f32x4 b) {
    unsigned u0, u1, u2, u3;
    asm("v_cvt_pk_bf16_f32 %0, %1, %2" : "=v"(u0) : "v"(a[0]), "v"(a[1]));
    asm("v_cvt_pk_bf16_f32 %0, %1, %2" : "=v"(u1) : "v"(a[2]), "v"(a[3]));
    asm("v_cvt_pk_bf16_f32 %0, %1, %2" : "=v"(u2) : "v"(b[0]), "v"(b[1]));
    asm("v_cvt_pk_bf16_f32 %0, %1, %2" : "=v"(u3) : "v"(b[2]), "v"(b[3]));
    u32x4 u; u[0] = u0; u[1] = u1; u[2] = u2; u[3] = u3;
    return __builtin_bit_cast(short8, u);
}

// ================= prep (no values pass) =================
// blocks [0,512): pq + score zero   [512,584): B_ext^T transpose
// [584,1608): location conv
__global__ void prep_kernel(const float* __restrict__ query, const float* __restrict__ Wq,
                            const float* __restrict__ Wi, const float* __restrict__ Wl,
                            const float* __restrict__ old_, const float* __restrict__ cum_,
                            const float* __restrict__ lk,
                            float* __restrict__ pq,
                            float* __restrict__ score, unsigned short* __restrict__ Bt,
                            unsigned short* __restrict__ convb) {
    __shared__ __align__(16) char smem[16640];
    int bid = blockIdx.x, tid = threadIdx.x;
    if (bid < 512) {
        // ---- pq + zero score ----
        float (*red)[64] = (float(*)[64])smem;
        int pid = bid;
        int gid = pid * 256 + tid;
        if (gid < M_TOT) score[gid] = 0.f;
        int b = pid >> 3, a0 = (pid & 7) * 64;
        int al = tid & 63, ks = tid >> 6;
        const float* qr = query + (size_t)b * DQ + ks * 256;
        const float* wc = Wq + (size_t)(ks * 256) * A_DIM + a0 + al;
        float acc = 0.f;
        #pragma unroll 8
        for (int k = 0; k < 256; ++k) acc += qr[k] * wc[(size_t)k * A_DIM];
        red[ks][al] = acc;
        __syncthreads();
        if (ks == 0)
            pq[b * A_DIM + a0 + al] = red[0][al] + red[1][al] + red[2][al] + red[3][al];
    } else if (bid < 584) {
        // ---- Bt transpose (stride KEXT2=576) ----
        float (*tile)[65] = (float(*)[65])smem;
        int tb = bid - 512;
        if (tb < 64) {
            int k0 = (tb >> 3) * 64, a0 = (tb & 7) * 64;
            int al = tid & 63, ko = tid >> 6;
            #pragma unroll
            for (int j = 0; j < 16; ++j) {
                int kl = j * 4 + ko;
                tile[kl][al] = Wi[(size_t)(k0 + kl) * A_DIM + a0 + al];
            }
            __syncthreads();
            int kl2 = tid & 63, ao = tid >> 6;
            #pragma unroll
            for (int j = 0; j < 16; ++j) {
                int al2 = j * 4 + ao;
                Bt[(size_t)(a0 + al2) * KEXT2 + k0 + kl2] = f2bf(tile[kl2][al2]);
            }
        } else {
            int a0 = (tb - 64) * 64;
            int al = tid & 63, ko = tid >> 6;
            #pragma unroll
            for (int j = 0; j < 8; ++j) {
                int kl = j * 4 + ko;
                tile[kl][al] = Wl[(size_t)kl * A_DIM + a0 + al];
            }
            __syncthreads();
            int kl2 = tid & 31, ao = tid >> 5;
            #pragma unroll
            for (int j = 0; j < 8; ++j) {
                int al2 = j * 8 + ao;
                Bt[(size_t)(a0 + al2) * KEXT2 + DV + kl2] = f2bf(tile[kl2][al2]);
            }
            // zero-pad k in [544,576)
            #pragma unroll
            for (int j = 0; j < 8; ++j) {
                int idx = j * 256 + tid;
                int a_l = idx >> 5, kp = idx & 31;
                Bt[(size_t)(a0 + a_l) * KEXT2 + 544 + kp] = 0;
            }
        }
    } else {
        // ---- conv (rows widened to 64: [32 conv | 32 zeros]) ----
        float* sOld = (float*)smem;            // 94
        float* sCum = sOld + 94;               // 94
        float* sLK  = sCum + 94;               // 1984
        int cid = bid - 584;
        int b = cid >> 4, t0 = (cid & 15) * 64;
        int tl = tid & 63, fg = tid >> 6;
        for (int j = tid; j < 94; j += 256) {
            int tt = t0 - 15 + j;
            bool ok = (tt >= 0 && tt < T);
            sOld[j] = ok ? old_[b * T + tt] : 0.f;
            sCum[j] = ok ? cum_[b * T + tt] : 0.f;
        }
        for (int j = tid; j < KW * 2 * F_DIM; j += 256) sLK[j] = lk[j];
        __syncthreads();
        float acc[8];
        #pragma unroll
        for (int f = 0; f < 8; ++f) acc[f] = 0.f;
        for (int k = 0; k < KW; ++k) {
            float o = sOld[tl + k], c = sCum[tl + k];
            const float* lo = &sLK[(k * 2 + 0) * F_DIM + fg * 8];
            const float* lc = &sLK[(k * 2 + 1) * F_DIM + fg * 8];
            #pragma unroll
            for (int f = 0; f < 8; ++f) acc[f] += o * lo[f] + c * lc[f];
        }
        short8 pk;
        #pragma unroll
        for (int f = 0; f < 8; ++f) pk[f] = (short)f2bf(acc[f]);
        unsigned short* dst = convb + (size_t)(b * T + t0 + tl) * 64 + fg * 8;
        *(short8*)dst = pk;
        *(short8*)(dst + 32) = (short8)0;      // zero-pad
    }
}

// ================= fused GEMM + tanh + dot(v_w) -> score =================
// grid 2048 XCD-swizzled (4 nq-siblings share A-panel on one XCD); block 128x128,
// 4 waves, wave 64x64. NO LDS, NO BARRIERS: operands loaded direct to registers.
//  - A fragments from values (fp32, L3-resident; wave read = 16 rows x 64B
//    contiguous), cvt to bf16 in-reg via v_cvt_pk_bf16_f32.
//  - B fragments from Bt (576 KB, L2-resident).
//  - conv chunk (k=512..544): A from convb bf16, B from Bt Wl rows; single
//    MFMA group (pad regions never read).
// Latency hidden by 12 waves/CU (3 blocks) with zero sync points.
__launch_bounds__(256, 3)
__global__ void gemm_score(const float* __restrict__ values,
                           const unsigned short* __restrict__ Bt,
                           const unsigned short* __restrict__ convb,
                           const float* __restrict__ pq,
                           const float* __restrict__ vw,
                           float* __restrict__ score) {
    int tid = threadIdx.x;
    int x = blockIdx.x & 7, l = blockIdx.x >> 3;
    int mt = x * 64 + (l >> 2), nq = l & 3;
    int m0 = mt * 128, n0 = nq * 128;
    int b = m0 >> 10;
    int w = tid >> 6, lane = tid & 63, q = lane >> 4, l15 = lane & 15;
    int wm = w & 1, wn = w >> 1;
    int arow = m0 + wm * 64 + l15;
    int bcol = n0 + wn * 64 + l15;
    // per-fragment base pointers (advance by 64 elems per chunk; h*32 stays imm)
    const float* aP0 = values + (size_t)(arow +  0) * DV + q * 8;
    const float* aP1 = values + (size_t)(arow + 16) * DV + q * 8;
    const float* aP2 = values + (size_t)(arow + 32) * DV + q * 8;
    const float* aP3 = values + (size_t)(arow + 48) * DV + q * 8;
    const unsigned short* bP0 = Bt + (size_t)(bcol +  0) * KEXT2 + q * 8;
    const unsigned short* bP1 = Bt + (size_t)(bcol + 16) * KEXT2 + q * 8;
    const unsigned short* bP2 = Bt + (size_t)(bcol + 32) * KEXT2 + q * 8;
    const unsigned short* bP3 = Bt + (size_t)(bcol + 48) * KEXT2 + q * 8;

    f32x4 acc[4][4];
    #pragma unroll
    for (int mi = 0; mi < 4; ++mi)
        #pragma unroll
        for (int ni = 0; ni < 4; ++ni) acc[mi][ni] = (f32x4)0.f;

    #pragma unroll 1
    for (int c = 0; c < 8; ++c) {
        #pragma unroll
        for (int h = 0; h < 2; ++h) {
            f32x4 lo[4], hi[4];
            short8 bfr[4], af[4];
            lo[0] = *(const f32x4*)(aP0 + h * 32); hi[0] = *(const f32x4*)(aP0 + h * 32 + 4);
            lo[1] = *(const f32x4*)(aP1 + h * 32); hi[1] = *(const f32x4*)(aP1 + h * 32 + 4);
            lo[2] = *(const f32x4*)(aP2 + h * 32); hi[2] = *(const f32x4*)(aP2 + h * 32 + 4);
            lo[3] = *(const f32x4*)(aP3 + h * 32); hi[3] = *(const f32x4*)(aP3 + h * 32 + 4);
            bfr[0] = *(const short8*)(bP0 + h * 32);
            bfr[1] = *(const short8*)(bP1 + h * 32);
            bfr[2] = *(const short8*)(bP2 + h * 32);
            bfr[3] = *(const short8*)(bP3 + h * 32);
            #pragma unroll
            for (int mi = 0; mi < 4; ++mi) af[mi] = cvt8(lo[mi], hi[mi]);
            #pragma unroll
            for (int mi = 0; mi < 4; ++mi)
                #pragma unroll
                for (int ni = 0; ni < 4; ++ni)
                    acc[mi][ni] = __builtin_amdgcn_mfma_f32_16x16x32_bf16(af[mi], bfr[ni], acc[mi][ni], 0, 0, 0);
        }
        aP0 += 64; aP1 += 64; aP2 += 64; aP3 += 64;
        bP0 += 64; bP1 += 64; bP2 += 64; bP3 += 64;
    }
    // ---- conv chunk: k = 512..544 (A from convb, B = Wl rows of Bt)
    {
        short8 af[4], bfr[4];
        const unsigned short* cP = convb + (size_t)arow * 64 + q * 8;
        af[0] = *(const short8*)(cP);
        af[1] = *(const short8*)(cP + 16 * 64);
        af[2] = *(const short8*)(cP + 32 * 64);
        af[3] = *(const short8*)(cP + 48 * 64);
        bfr[0] = *(const short8*)(bP0);   // bP* already advanced to k=512
        bfr[1] = *(const short8*)(bP1);
        bfr[2] = *(const short8*)(bP2);
        bfr[3] = *(const short8*)(bP3);
        #pragma unroll
        for (int mi = 0; mi < 4; ++mi)
            #pragma unroll
            for (int ni = 0; ni < 4; ++ni)
                acc[mi][ni] = __builtin_amdgcn_mfma_f32_16x16x32_bf16(af[mi], bfr[ni], acc[mi][ni], 0, 0, 0);
    }
    // ---- epilogue: partial score over 128 cols -> atomicAdd
    float pqv[4], vwv[4];
    #pragma unroll
    for (int ni = 0; ni < 4; ++ni) {
        int col = n0 + wn * 64 + ni * 16 + l15;
        pqv[ni] = pq[b * A_DIM + col];
        vwv[ni] = vw[col];
    }
    #pragma unroll
    for (int mi = 0; mi < 4; ++mi) {
        #pragma unroll
        for (int r = 0; r < 4; ++r) {
            float s = 0.f;
            #pragma unroll
            for (int ni = 0; ni < 4; ++ni) {
                float xv = acc[mi][ni][r] + pqv[ni];
                s += tanh_fast(xv) * vwv[ni];
            }
            #pragma unroll
            for (int off = 1; off < 16; off <<= 1) s += __shfl_xor(s, off, 64);
            if (l15 == 0)
                atomicAdd(&score[m0 + wm * 64 + mi * 16 + q * 4 + r], s);
        }
    }
}

// ================= softmax + forward-attention recursion =================
__global__ void softmax_fwd(const float* __restrict__ score,
                            const float* __restrict__ alpha,
                            const float* __restrict__ cum,
                            float* __restrict__ out) {
    int b = blockIdx.x, t = threadIdx.x;   // 1024 threads
    __shared__ float sred[16];
    __shared__ float sbc;
    float sc = score[b * T + t];
    int wid = t >> 6, lane = t & 63;
    float m = sc;
    #pragma unroll
    for (int off = 32; off; off >>= 1) m = fmaxf(m, __shfl_xor(m, off, 64));
    if (lane == 0) sred[wid] = m;
    __syncthreads();
    if (t == 0) { float mm = sred[0]; for (int i = 1; i < 16; ++i) mm = fmaxf(mm, sred[i]); sbc = mm; }
    __syncthreads();
    float M = sbc;
    float e = __expf(sc - M);
    float s = e;
    #pragma unroll
    for (int off = 32; off; off >>= 1) s += __shfl_xor(s, off, 64);
    __syncthreads();
    if (lane == 0) sred[wid] = s;
    __syncthreads();
    if (t == 0) { float ss = 0.f; for (int i = 0; i < 16; ++i) ss += sred[i]; sbc = ss; }
    __syncthreads();
    float sn = e / sbc;
    float a_t = alpha[b * T + t];
    float a_p = (t > 0) ? alpha[b * T + t - 1] : 0.f;
    float ua = (0.5f * (a_t + a_p) + 1e-8f) * sn;
    float u = ua;
    #pragma unroll
    for (int off = 32; off; off >>= 1) u += __shfl_xor(u, off, 64);
    __syncthreads();
    if (lane == 0) sred[wid] = u;
    __syncthreads();
    if (t == 0) { float ss = 0.f; for (int i = 0; i < 16; ++i) ss += sred[i]; sbc = ss; }
    __syncthreads();
    float wgt = ua / sbc;
    float* attnw  = out + B * DV;
    float* ncum   = attnw + B * T;
    float* nold   = ncum + B * T;
    float* nalpha = nold + B * T;
    attnw[b * T + t]  = wgt;
    ncum[b * T + t]   = cum[b * T + t] + sn;
    nold[b * T + t]   = wgt;
    nalpha[b * T + t] = wgt;
    if (t < DV) out[b * DV + t] = 0.f;   // zero context region for accumulation
}

// ================= context = attn_weights @ values (fp32) =================
// grid 2048 = 64 b x 16 tq(64 t) x 2 dh(256 d); thr: sub=tid>>6 (16-t slice), dg=tid&63
__global__ void context_kernel(const float* __restrict__ values,
                               float* __restrict__ out) {
    __shared__ float red[4][256];
    const float* attnw = out + B * DV;
    int b = blockIdx.x >> 5, tq = (blockIdx.x >> 1) & 15, dh = blockIdx.x & 1;
    int sub = threadIdx.x >> 6, dg = threadIdx.x & 63;
    int t0 = tq * 64 + sub * 16;
    int d0 = dh * 256 + dg * 4;
    float acc[4];
    #pragma unroll
    for (int f = 0; f < 4; ++f) acc[f] = 0.f;
    for (int tt = 0; tt < 16; ++tt) {
        int t = t0 + tt;
        float wgt = attnw[b * T + t];
        float4 xv = *(const float4*)(values + (size_t)(b * T + t) * DV + d0);
        acc[0] += wgt * xv.x; acc[1] += wgt * xv.y;
        acc[2] += wgt * xv.z; acc[3] += wgt * xv.w;
    }
    #pragma unroll
    for (int f = 0; f < 4; ++f) red[sub][dg * 4 + f] = acc[f];
    __syncthreads();
    if (sub == 0) {
        #pragma unroll
        for (int f = 0; f < 4; ++f) {
            int di = dg * 4 + f;
            float s = red[0][di] + red[1][di] + red[2][di] + red[3][di];
            atomicAdd(&out[b * DV + dh * 256 + di], s);
        }
    }
}

extern "C" void kernel_launch(void* const* d_in, const int* in_sizes, int n_in,
                              void* d_out, int out_size, void* d_ws, size_t ws_size,
                              hipStream_t stream) {
    const float* query  = (const float*)d_in[0];
    const float* values = (const float*)d_in[1];
    const float* cum    = (const float*)d_in[2];
    const float* old_   = (const float*)d_in[3];
    const float* alpha  = (const float*)d_in[4];
    const float* Wq     = (const float*)d_in[5];
    const float* Wi     = (const float*)d_in[6];
    const float* vw     = (const float*)d_in[7];
    // d_in[8] = v_b : dropped (softmax shift-invariant)
    const float* lk     = (const float*)d_in[9];
    const float* Wl     = (const float*)d_in[10];
    float* out = (float*)d_out;
    char* ws = (char*)d_ws;
    float* ws_pq            = (float*)(ws);                     // 128 KiB
    float* ws_score         = (float*)(ws + 131072);            // 256 KiB
    unsigned short* ws_Bt   = (unsigned short*)(ws + 393216);   // 512*576*2 = 576 KiB
    unsigned short* ws_conv = (unsigned short*)(ws + 1048576);  // 65536*64*2 = 8 MiB

    prep_kernel<<<1608, 256, 0, stream>>>(query, Wq, Wi, Wl, old_, cum, lk,
                                          ws_pq, ws_score, ws_Bt, ws_conv);
    gemm_score<<<2048, 256, 0, stream>>>(values, ws_Bt, ws_conv, ws_pq, vw, ws_score);
    softmax_fwd<<<64, 1024, 0, stream>>>(ws_score, alpha, cum, out);
    context_kernel<<<2048, 256, 0, stream>>>(values, out);
}

// Round 10
// 316.893 us; speedup vs baseline: 1.2833x; 1.2833x over previous
//
#include <hip/hip_runtime.h>
#include <hip/hip_bf16.h>
#include <cstdint>
#include <cstddef>

#define B 64
#define T 1024
#define DQ 1024
#define DV 512
#define A_DIM 512
#define F_DIM 32
#define KW 31
#define M_TOT (B*T)
#define KEXT2 576     // DV + 64 (conv 32 + zero-pad 32)

typedef __attribute__((ext_vector_type(8))) short short8;
typedef __attribute__((ext_vector_type(4))) float f32x4;
typedef __attribute__((ext_vector_type(4))) unsigned u32x4;

static __device__ __forceinline__ unsigned short f2bf(float f) {
    unsigned int u = __builtin_bit_cast(unsigned int, f);
    u += 0x7fffu + ((u >> 16) & 1u);   // RNE
    return (unsigned short)(u >> 16);
}
static __device__ __forceinline__ float tanh_fast(float x) {
    float e = __expf(2.0f * x);
    return 1.0f - 2.0f * __builtin_amdgcn_rcpf(e + 1.0f);
}
// hardware packed fp32->bf16: one v_cvt_pk_bf16_f32 per element-pair
static __device__ __forceinline__ short8 cvt8(f32x4 a, f32x4 b) {
    unsigned u0, u1, u2, u3;
    asm("v_cvt_pk_bf16_f32 %0, %1, %2" : "=v"(u0) : "v"(a[0]), "v"(a[1]));
    asm("v_cvt_pk_bf16_f32 %0, %1, %2" : "=v"(u1) : "v"(a[2]), "v"(a[3]));
    asm("v_cvt_pk_bf16_f32 %0, %1, %2" : "=v"(u2) : "v"(b[0]), "v"(b[1]));
    asm("v_cvt_pk_bf16_f32 %0, %1, %2" : "=v"(u3) : "v"(b[2]), "v"(b[3]));
    u32x4 u; u[0] = u0; u[1] = u1; u[2] = u2; u[3] = u3;
    return __builtin_bit_cast(short8, u);
}

// async global -> LDS, 16 B per lane; lptr wave-uniform base, lane i -> +i*16
#define LDSDMA16(gptr, lptr)                                                        \
    __builtin_amdgcn_global_load_lds(                                               \
        (const __attribute__((address_space(1))) void*)(const void*)(gptr),         \
        (__attribute__((address_space(3))) void*)(void*)(lptr), 16, 0, 0)

// ================= prep (no values pass) =================
// blocks [0,512): pq + score zero   [512,584): B_ext^T transpose
// [584,1608): location conv
__global__ void prep_kernel(const float* __restrict__ query, const float* __restrict__ Wq,
                            const float* __restrict__ Wi, const float* __restrict__ Wl,
                            const float* __restrict__ old_, const float* __restrict__ cum_,
                            const float* __restrict__ lk,
                            float* __restrict__ pq,
                            float* __restrict__ score, unsigned short* __restrict__ Bt,
                            unsigned short* __restrict__ convb) {
    __shared__ __align__(16) char smem[16640];
    int bid = blockIdx.x, tid = threadIdx.x;
    if (bid < 512) {
        // ---- pq + zero score ----
        float (*red)[64] = (float(*)[64])smem;
        int pid = bid;
        int gid = pid * 256 + tid;
        if (gid < M_TOT) score[gid] = 0.f;
        int b = pid >> 3, a0 = (pid & 7) * 64;
        int al = tid & 63, ks = tid >> 6;
        const float* qr = query + (size_t)b * DQ + ks * 256;
        const float* wc = Wq + (size_t)(ks * 256) * A_DIM + a0 + al;
        float acc = 0.f;
        #pragma unroll 8
        for (int k = 0; k < 256; ++k) acc += qr[k] * wc[(size_t)k * A_DIM];
        red[ks][al] = acc;
        __syncthreads();
        if (ks == 0)
            pq[b * A_DIM + a0 + al] = red[0][al] + red[1][al] + red[2][al] + red[3][al];
    } else if (bid < 584) {
        // ---- Bt transpose (stride KEXT2=576) ----
        float (*tile)[65] = (float(*)[65])smem;
        int tb = bid - 512;
        if (tb < 64) {
            int k0 = (tb >> 3) * 64, a0 = (tb & 7) * 64;
            int al = tid & 63, ko = tid >> 6;
            #pragma unroll
            for (int j = 0; j < 16; ++j) {
                int kl = j * 4 + ko;
                tile[kl][al] = Wi[(size_t)(k0 + kl) * A_DIM + a0 + al];
            }
            __syncthreads();
            int kl2 = tid & 63, ao = tid >> 6;
            #pragma unroll
            for (int j = 0; j < 16; ++j) {
                int al2 = j * 4 + ao;
                Bt[(size_t)(a0 + al2) * KEXT2 + k0 + kl2] = f2bf(tile[kl2][al2]);
            }
        } else {
            int a0 = (tb - 64) * 64;
            int al = tid & 63, ko = tid >> 6;
            #pragma unroll
            for (int j = 0; j < 8; ++j) {
                int kl = j * 4 + ko;
                tile[kl][al] = Wl[(size_t)kl * A_DIM + a0 + al];
            }
            __syncthreads();
            int kl2 = tid & 31, ao = tid >> 5;
            #pragma unroll
            for (int j = 0; j < 8; ++j) {
                int al2 = j * 8 + ao;
                Bt[(size_t)(a0 + al2) * KEXT2 + DV + kl2] = f2bf(tile[kl2][al2]);
            }
            // zero-pad k in [544,576)
            #pragma unroll
            for (int j = 0; j < 8; ++j) {
                int idx = j * 256 + tid;
                int a_l = idx >> 5, kp = idx & 31;
                Bt[(size_t)(a0 + a_l) * KEXT2 + 544 + kp] = 0;
            }
        }
    } else {
        // ---- conv (rows widened to 64: [32 conv | 32 zeros]) ----
        float* sOld = (float*)smem;            // 94
        float* sCum = sOld + 94;               // 94
        float* sLK  = sCum + 94;               // 1984
        int cid = bid - 584;
        int b = cid >> 4, t0 = (cid & 15) * 64;
        int tl = tid & 63, fg = tid >> 6;
        for (int j = tid; j < 94; j += 256) {
            int tt = t0 - 15 + j;
            bool ok = (tt >= 0 && tt < T);
            sOld[j] = ok ? old_[b * T + tt] : 0.f;
            sCum[j] = ok ? cum_[b * T + tt] : 0.f;
        }
        for (int j = tid; j < KW * 2 * F_DIM; j += 256) sLK[j] = lk[j];
        __syncthreads();
        float acc[8];
        #pragma unroll
        for (int f = 0; f < 8; ++f) acc[f] = 0.f;
        for (int k = 0; k < KW; ++k) {
            float o = sOld[tl + k], c = sCum[tl + k];
            const float* lo = &sLK[(k * 2 + 0) * F_DIM + fg * 8];
            const float* lc = &sLK[(k * 2 + 1) * F_DIM + fg * 8];
            #pragma unroll
            for (int f = 0; f < 8; ++f) acc[f] += o * lo[f] + c * lc[f];
        }
        short8 pk;
        #pragma unroll
        for (int f = 0; f < 8; ++f) pk[f] = (short)f2bf(acc[f]);
        unsigned short* dst = convb + (size_t)(b * T + t0 + tl) * 64 + fg * 8;
        *(short8*)dst = pk;
        *(short8*)(dst + 32) = (short8)0;      // zero-pad
    }
}

// ================= fused GEMM + tanh + dot(v_w) -> score =================
// grid 2048 XCD-swizzled; block 128x128, BK=64, 9 chunks; 4 waves, wave 64x64,
// 3 blocks/CU. A stored in LDS as BF16 (16KB single buffer), converted at
// stage time in registers (T14 issue-early/write-late):
//   iter c: issue A(c+1) fp32 loads + B(c+1) DMA -> compute(c) ->
//           lgkm-barrier -> cvt+ds_write A(c+1) -> __syncthreads.
// The __syncthreads' vmcnt(0) only drains B(c+1) DMA issued a full compute
// earlier. LDS port traffic 96KB/chunk/block (was 144KB with fp32 A).
// Both A,B use the 8-slot XOR swizzle: phys 16B-slot = (seg + row) & 7.
__launch_bounds__(256, 3)
__global__ void gemm_score(const float* __restrict__ values,
                           const unsigned short* __restrict__ Bt,
                           const unsigned short* __restrict__ convb,
                           const float* __restrict__ pq,
                           const float* __restrict__ vw,
                           float* __restrict__ score) {
    __shared__ __align__(16) short sA[128 * 64];      // 16KB bf16 A (single buf)
    __shared__ __align__(16) short sB[2][128 * 64];   // 2 x 16KB bf16 B
    __shared__ float sPQ[128];
    __shared__ float sVW[128];
    int tid = threadIdx.x;
    // XCD swizzle: 4 nq-siblings (same mt) land on one XCD, adjacent in time
    int x = blockIdx.x & 7, l = blockIdx.x >> 3;
    int mt = x * 64 + (l >> 2), nq = l & 3;
    int m0 = mt * 128, n0 = nq * 128;
    int b = m0 >> 10;
    if (tid < 128) { sPQ[tid] = pq[b * A_DIM + n0 + tid]; sVW[tid] = vw[n0 + tid]; }
    int w = tid >> 6, lane = tid & 63, q = lane >> 4, l15 = lane & 15;
    int wm = w & 1, wn = w >> 1;
    // stage geometry: slot = j*256+tid -> row = j*32+(tid>>3); phys 16B-slot
    // (tid&7) holds logical seg = ((tid&7) - row) & 7
    int srow = tid >> 3, sseg = ((tid & 7) - srow) & 7;
    const float* aSrc[4];
    #pragma unroll
    for (int j = 0; j < 4; ++j)
        aSrc[j] = values + (size_t)(m0 + j * 32 + srow) * DV + sseg * 8;
    const unsigned short* bBase = Bt + (size_t)(n0 + srow) * KEXT2 + sseg * 8;

    f32x4 acc[4][4];
    #pragma unroll
    for (int mi = 0; mi < 4; ++mi)
        #pragma unroll
        for (int ni = 0; ni < 4; ++ni) acc[mi][ni] = (f32x4)0.f;

    // ---- prologue: stage chunk 0 (A reg->cvt->LDS, B DMA)
    {
        f32x4 plo[4], phi[4];
        #pragma unroll
        for (int j = 0; j < 4; ++j) {
            plo[j] = *(const f32x4*)(aSrc[j]);
            phi[j] = *(const f32x4*)(aSrc[j] + 4);
        }
        #pragma unroll
        for (int j = 0; j < 4; ++j)
            LDSDMA16(bBase + (size_t)j * 32 * KEXT2, &sB[0][(j * 256 + w * 64) * 8]);
        #pragma unroll
        for (int j = 0; j < 4; ++j)
            *(short8*)&sA[(j * 256 + tid) * 8] = cvt8(plo[j], phi[j]);
    }
    __syncthreads();

    #pragma unroll 1
    for (int c = 0; c <= 8; ++c) {
        int nxt = c + 1;
        f32x4 lo4[4], hi4[4];
        short8 cv[4];
        // ---- issue stage for chunk c+1 (loads in flight across compute)
        if (nxt < 8) {
            #pragma unroll
            for (int j = 0; j < 4; ++j) {
                lo4[j] = *(const f32x4*)(aSrc[j] + nxt * 64);
                hi4[j] = *(const f32x4*)(aSrc[j] + nxt * 64 + 4);
            }
            #pragma unroll
            for (int j = 0; j < 4; ++j)
                LDSDMA16(bBase + (size_t)j * 32 * KEXT2 + nxt * 64,
                         &sB[nxt & 1][(j * 256 + w * 64) * 8]);
        } else if (nxt == 8) {
            #pragma unroll
            for (int j = 0; j < 4; ++j)
                cv[j] = *(const short8*)(convb + (size_t)(m0 + j * 32 + srow) * 64 + sseg * 8);
            #pragma unroll
            for (int j = 0; j < 4; ++j)
                LDSDMA16(bBase + (size_t)j * 32 * KEXT2 + 8 * 64,
                         &sB[0][(j * 256 + w * 64) * 8]);
        }
        // ---- compute chunk c from sA, sB[c&1]: 2 k-halves x 16 MFMAs
        #pragma unroll
        for (int h = 0; h < 2; ++h) {
            short8 af[4], bfr[4];
            int sgl = h * 4 + q;
            #pragma unroll
            for (int mi = 0; mi < 4; ++mi) {
                int r = wm * 64 + mi * 16 + l15;
                af[mi] = *(const short8*)&sA[r * 64 + (((sgl + r) & 7) << 3)];
            }
            #pragma unroll
            for (int ni = 0; ni < 4; ++ni) {
                int r = wn * 64 + ni * 16 + l15;
                bfr[ni] = *(const short8*)&sB[c & 1][r * 64 + (((sgl + r) & 7) << 3)];
            }
            #pragma unroll
            for (int mi = 0; mi < 4; ++mi)
                #pragma unroll
                for (int ni = 0; ni < 4; ++ni)
                    acc[mi][ni] = __builtin_amdgcn_mfma_f32_16x16x32_bf16(af[mi], bfr[ni], acc[mi][ni], 0, 0, 0);
        }
        // ---- write-late: all waves done reading sA, then overwrite with c+1
        if (nxt <= 8) {
            asm volatile("s_waitcnt lgkmcnt(0)" ::: "memory");   // own ds_reads done
            __builtin_amdgcn_s_barrier();                        // collective
            __builtin_amdgcn_sched_barrier(0);
            short8 pk[4];
            if (nxt < 8) {
                #pragma unroll
                for (int j = 0; j < 4; ++j) pk[j] = cvt8(lo4[j], hi4[j]);
            } else {
                #pragma unroll
                for (int j = 0; j < 4; ++j) pk[j] = cv[j];
            }
            #pragma unroll
            for (int j = 0; j < 4; ++j)
                *(short8*)&sA[(j * 256 + tid) * 8] = pk[j];
            __syncthreads();   // A writes visible; drains B(c+1) DMA (long in flight)
        }
    }
    // ---- epilogue: partial score over 128 cols -> atomicAdd
    #pragma unroll
    for (int mi = 0; mi < 4; ++mi) {
        #pragma unroll
        for (int r = 0; r < 4; ++r) {
            float s = 0.f;
            #pragma unroll
            for (int ni = 0; ni < 4; ++ni) {
                int col = wn * 64 + ni * 16 + l15;
                float xv = acc[mi][ni][r] + sPQ[col];
                s += tanh_fast(xv) * sVW[col];
            }
            #pragma unroll
            for (int off = 1; off < 16; off <<= 1) s += __shfl_xor(s, off, 64);
            if (l15 == 0)
                atomicAdd(&score[m0 + wm * 64 + mi * 16 + q * 4 + r], s);
        }
    }
}

// ================= softmax + forward-attention recursion =================
__global__ void softmax_fwd(const float* __restrict__ score,
                            const float* __restrict__ alpha,
                            const float* __restrict__ cum,
                            float* __restrict__ out) {
    int b = blockIdx.x, t = threadIdx.x;   // 1024 threads
    __shared__ float sred[16];
    __shared__ float sbc;
    float sc = score[b * T + t];
    int wid = t >> 6, lane = t & 63;
    float m = sc;
    #pragma unroll
    for (int off = 32; off; off >>= 1) m = fmaxf(m, __shfl_xor(m, off, 64));
    if (lane == 0) sred[wid] = m;
    __syncthreads();
    if (t == 0) { float mm = sred[0]; for (int i = 1; i < 16; ++i) mm = fmaxf(mm, sred[i]); sbc = mm; }
    __syncthreads();
    float M = sbc;
    float e = __expf(sc - M);
    float s = e;
    #pragma unroll
    for (int off = 32; off; off >>= 1) s += __shfl_xor(s, off, 64);
    __syncthreads();
    if (lane == 0) sred[wid] = s;
    __syncthreads();
    if (t == 0) { float ss = 0.f; for (int i = 0; i < 16; ++i) ss += sred[i]; sbc = ss; }
    __syncthreads();
    float sn = e / sbc;
    float a_t = alpha[b * T + t];
    float a_p = (t > 0) ? alpha[b * T + t - 1] : 0.f;
    float ua = (0.5f * (a_t + a_p) + 1e-8f) * sn;
    float u = ua;
    #pragma unroll
    for (int off = 32; off; off >>= 1) u += __shfl_xor(u, off, 64);
    __syncthreads();
    if (lane == 0) sred[wid] = u;
    __syncthreads();
    if (t == 0) { float ss = 0.f; for (int i = 0; i < 16; ++i) ss += sred[i]; sbc = ss; }
    __syncthreads();
    float wgt = ua / sbc;
    float* attnw  = out + B * DV;
    float* ncum   = attnw + B * T;
    float* nold   = ncum + B * T;
    float* nalpha = nold + B * T;
    attnw[b * T + t]  = wgt;
    ncum[b * T + t]   = cum[b * T + t] + sn;
    nold[b * T + t]   = wgt;
    nalpha[b * T + t] = wgt;
    if (t < DV) out[b * DV + t] = 0.f;   // zero context region for accumulation
}

// ================= context = attn_weights @ values (fp32) =================
// grid 2048 = 64 b x 16 tq(64 t) x 2 dh(256 d); thr: sub=tid>>6 (16-t slice), dg=tid&63
__global__ void context_kernel(const float* __restrict__ values,
                               float* __restrict__ out) {
    __shared__ float red[4][256];
    const float* attnw = out + B * DV;
    int b = blockIdx.x >> 5, tq = (blockIdx.x >> 1) & 15, dh = blockIdx.x & 1;
    int sub = threadIdx.x >> 6, dg = threadIdx.x & 63;
    int t0 = tq * 64 + sub * 16;
    int d0 = dh * 256 + dg * 4;
    float acc[4];
    #pragma unroll
    for (int f = 0; f < 4; ++f) acc[f] = 0.f;
    for (int tt = 0; tt < 16; ++tt) {
        int t = t0 + tt;
        float wgt = attnw[b * T + t];
        float4 xv = *(const float4*)(values + (size_t)(b * T + t) * DV + d0);
        acc[0] += wgt * xv.x; acc[1] += wgt * xv.y;
        acc[2] += wgt * xv.z; acc[3] += wgt * xv.w;
    }
    #pragma unroll
    for (int f = 0; f < 4; ++f) red[sub][dg * 4 + f] = acc[f];
    __syncthreads();
    if (sub == 0) {
        #pragma unroll
        for (int f = 0; f < 4; ++f) {
            int di = dg * 4 + f;
            float s = red[0][di] + red[1][di] + red[2][di] + red[3][di];
            atomicAdd(&out[b * DV + dh * 256 + di], s);
        }
    }
}

extern "C" void kernel_launch(void* const* d_in, const int* in_sizes, int n_in,
                              void* d_out, int out_size, void* d_ws, size_t ws_size,
                              hipStream_t stream) {
    const float* query  = (const float*)d_in[0];
    const float* values = (const float*)d_in[1];
    const float* cum    = (const float*)d_in[2];
    const float* old_   = (const float*)d_in[3];
    const float* alpha  = (const float*)d_in[4];
    const float* Wq     = (const float*)d_in[5];
    const float* Wi     = (const float*)d_in[6];
    const float* vw     = (const float*)d_in[7];
    // d_in[8] = v_b : dropped (softmax shift-invariant)
    const float* lk     = (const float*)d_in[9];
    const float* Wl     = (const float*)d_in[10];
    float* out = (float*)d_out;
    char* ws = (char*)d_ws;
    float* ws_pq            = (float*)(ws);                     // 128 KiB
    float* ws_score         = (float*)(ws + 131072);            // 256 KiB
    unsigned short* ws_Bt   = (unsigned short*)(ws + 393216);   // 512*576*2 = 576 KiB
    unsigned short* ws_conv = (unsigned short*)(ws + 1048576);  // 65536*64*2 = 8 MiB

    prep_kernel<<<1608, 256, 0, stream>>>(query, Wq, Wi, Wl, old_, cum, lk,
                                          ws_pq, ws_score, ws_Bt, ws_conv);
    gemm_score<<<2048, 256, 0, stream>>>(values, ws_Bt, ws_conv, ws_pq, vw, ws_score);
    softmax_fwd<<<64, 1024, 0, stream>>>(ws_score, alpha, cum, out);
    context_kernel<<<2048, 256, 0, stream>>>(values, out);
}